// Round 8
// baseline (1168.379 us; speedup 1.0000x reference)
//
#include <hip/hip_runtime.h>
#include <math.h>

#define B_ 128
#define J_ 32
#define I_ 1152
#define N_ 16
#define TI 16          // i per stage step
#define STEPS 4        // stage steps per block -> 64 i per block
#define NT (I_/(TI*STEPS))   // 18 blocks per example in i

// ws layout (float offsets)
#define OFF_W   0
#define OFF_S1  65536
#define OFF_S2  131072
#define OFF_SC0 262144
#define OFF_SC1 266240
#define OFF_M0  270336
#define OFF_M1  274432
#define OFF_TK  278528     // 4 ticket arrays x 128 ints

// ---------------------------------------------------------------------------
// Dispatch 1: zero phase (folded) + s0[b,j] = sum_i U, fused squash -> w.
// One block per (b,j). Zero targets are only consumed by LATER dispatches.
__global__ __launch_bounds__(256) void sumv_kernel(const float* __restrict__ U,
        const float* __restrict__ bias, float* __restrict__ ws,
        float* __restrict__ ent) {
    int bj  = blockIdx.x;
    int b = bj >> 5, j = bj & 31;
    int tid = threadIdx.x;           // 256
    int gb = bj * 256 + tid;

    // folded zeroing (single writer per slot; no same-dispatch reader)
    if (gb < 2 * 65536) ws[OFF_S1 + gb] = 0.f;                 // s1, s2
    if (gb < 2 * 4096)  ws[OFF_SC0 + gb] = 0.f;                // sc0, sc1
    if (gb < 4 * B_)    ((int*)(ws + OFF_TK))[gb] = 0;         // tickets
    if (gb < B_) {                                             // entropy
        ent[gb * 3]     = logf(32.f);
        ent[gb * 3 + 1] = 0.f;
        ent[gb * 3 + 2] = 0.f;
    }

    int nc  = tid & 3;
    int ip  = tid >> 2;              // 0..63
    const float4* base = (const float4*)(U + (size_t)bj * I_ * N_);
    float4 acc = make_float4(0.f, 0.f, 0.f, 0.f);
    for (int i = ip; i < I_; i += 64) {
        float4 u = base[i * 4 + nc];
        acc.x += u.x; acc.y += u.y; acc.z += u.z; acc.w += u.w;
    }
    __shared__ float4 lds[256];
    lds[nc * 64 + ip] = acc;
    __syncthreads();
    for (int s = 32; s >= 1; s >>= 1) {
        if (ip < s) {
            float4 a = lds[nc * 64 + ip], c = lds[nc * 64 + ip + s];
            a.x += c.x; a.y += c.y; a.z += c.z; a.w += c.w;
            lds[nc * 64 + ip] = a;
        }
        __syncthreads();
    }
    // fused vupdate mode 0: v0 = squash(s0/32 + bias), w = v0
    if (tid < 16) {                  // n = tid
        float sv = ((float*)&lds[(tid >> 2) * 64])[tid & 3] * (1.f / 32.f);
        float rs = sv;
        for (int k = 8; k; k >>= 1) rs += __shfl_xor(rs, k);
        float sb = (rs == 0.f) ? 0.f : sv + bias[j * N_ + tid];
        float sq = sb * sb;
        for (int k = 8; k; k >>= 1) sq += __shfl_xor(sq, k);
        float v = (sq / (1.f + sq)) * (sb / sqrtf(sq + 1e-8f));
        (ws + OFF_W)[(b * J_ + j) * N_ + tid] = v;
    }
}

// ---------------------------------------------------------------------------
// Streaming pass with fused per-b epilogue via last-block ticket.
// mode 0: scores[b,j] += sum_i p ;  mode 1: s[b,j,n] += sum_i p*U + entropy.
// fin 0: last block per b does stable top-K(scores) -> out_mask
// fin 1: last block per b does w += squash(s + bias)
// fin 2: last block per b does out_v = squash(s + bias)
__global__ __launch_bounds__(256) void pass_kernel(
        const float* __restrict__ U, float* __restrict__ w,
        const int* __restrict__ mask, float* __restrict__ scores,
        float* __restrict__ s_out, float* __restrict__ ent,
        int ent_idx, int mode, int* __restrict__ ticket,
        int* __restrict__ out_mask, int K,
        const float* __restrict__ bias, float* __restrict__ out_v, int fin) {
    __shared__ float4 lds[J_ * (TI * 4 + 1)];   // 33,280 B
    __shared__ float le[256];
    __shared__ int jlist[32];
    __shared__ int posj[32];
    __shared__ int nact_s;
    __shared__ int amlast;

    int bid = blockIdx.x;
    int b = bid / NT, chunk = bid % NT;
    int i0 = chunk * (TI * STEPS);
    int tid = threadIdx.x;           // 256
    int j = tid & 31, sub = tid >> 5;

    // compact active-j list
    if (tid < 32) {
        int act = mask ? (mask[b * J_ + tid] != 0) : 1;
        unsigned long long bal = __ballot(act);     // lanes 32..63 contribute 0
        unsigned m32 = (unsigned)bal;
        int p = __popc(m32 & ((1u << tid) - 1));
        if (act) jlist[p] = tid;
        posj[tid] = act ? p : -1;
        if (tid == 0) nact_s = __popc(m32);
    }
    __syncthreads();
    int nact = nact_s;
    int pj = posj[j];
    bool active = pj >= 0;
    int pjc = active ? pj : 0;

    const float4* wp = (const float4*)(w + (b * J_ + j) * N_);
    float4 w0 = wp[0], w1 = wp[1], w2 = wp[2], w3 = wp[3];

    float acc_sc = 0.f, acc_ent = 0.f;
    float4 a0 = make_float4(0,0,0,0), a1 = a0, a2 = a0, a3 = a0;

    const float4* Ub = (const float4*)U;
    int tot = nact * 64;

    for (int st = 0; st < STEPS; ++st) {
        int ibase = i0 + st * TI;
        for (int f = tid; f < tot; f += 256) {
            int jc = f >> 6, q = f & 63;
            lds[jc * 65 + q] = Ub[((size_t)(b * J_ + jlist[jc]) * I_ + ibase) * 4 + q];
        }
        __syncthreads();
        #pragma unroll
        for (int t2 = 0; t2 < 2; ++t2) {
            int ii = sub + t2 * 8;
            const float4* up = &lds[pjc * 65 + ii * 4];
            float4 u0 = up[0], u1 = up[1], u2 = up[2], u3 = up[3];
            float y = u0.x * w0.x + u0.y * w0.y + u0.z * w0.z + u0.w * w0.w
                    + u1.x * w1.x + u1.y * w1.y + u1.z * w1.z + u1.w * w1.w
                    + u2.x * w2.x + u2.y * w2.y + u2.z * w2.z + u2.w * w2.w
                    + u3.x * w3.x + u3.y * w3.y + u3.z * w3.z + u3.w * w3.w;
            float e = active ? __expf(y) : 0.f;
            float Z = e;
            for (int k = 16; k; k >>= 1) Z += __shfl_xor(Z, k);
            float p = e / Z;
            if (mode == 0) {
                acc_sc += p;
            } else {
                a0.x += p * u0.x; a0.y += p * u0.y; a0.z += p * u0.z; a0.w += p * u0.w;
                a1.x += p * u1.x; a1.y += p * u1.y; a1.z += p * u1.z; a1.w += p * u1.w;
                a2.x += p * u2.x; a2.y += p * u2.y; a2.z += p * u2.z; a2.w += p * u2.w;
                a3.x += p * u3.x; a3.y += p * u3.y; a3.z += p * u3.z; a3.w += p * u3.w;
                acc_ent += p * (y - __logf(Z));   // p*log(p), exact 0 for p==0
            }
        }
        __syncthreads();
    }

    if (mode == 0) {
        le[tid] = acc_sc;
        __syncthreads();
        if (tid < 32) {
            float t = 0.f;
            for (int s = 0; s < 8; s++) t += le[s * 32 + tid];
            atomicAdd(&scores[b * J_ + tid], t);
        }
    } else {
        float* ls = (float*)lds;
        float* myl = ls + tid * 16;
        ((float4*)myl)[0] = a0; ((float4*)myl)[1] = a1;
        ((float4*)myl)[2] = a2; ((float4*)myl)[3] = a3;
        le[tid] = acc_ent;
        __syncthreads();
        for (int idx = tid; idx < 512; idx += 256) {
            int jj = idx >> 4, nn = idx & 15;
            float t = 0.f;
            for (int s = 0; s < 8; s++) t += ls[(s * 32 + jj) * 16 + nn];
            atomicAdd(&s_out[(b * J_ + jj) * N_ + nn], t);
        }
        for (int s = 128; s >= 1; s >>= 1) {
            if (tid < s) le[tid] += le[tid + s];
            __syncthreads();
        }
        if (tid == 0) atomicAdd(&ent[b * 3 + ent_idx], -le[0] * (1.f / (float)I_));
    }

    // ---- fused per-b epilogue: last block of this b finishes the reduction
    __syncthreads();                 // drains all this block's vmem/atomic ops
    if (tid == 0) {
        __threadfence();
        int t = atomicAdd(&ticket[b], 1);
        amlast = (t == NT - 1) ? 1 : 0;
    }
    __syncthreads();
    if (!amlast) return;
    __threadfence();                 // acquire: see all blocks' atomics

    if (fin == 0) {
        // stable top-K (tie-break: lower index, as jax.lax.top_k)
        if (tid < 32) le[tid] = atomicAdd(&scores[b * 32 + tid], 0.f);
        __syncthreads();
        if (tid < 32) {
            float sv = le[tid];
            int rank = 0;
            for (int jj = 0; jj < 32; jj++) {
                float o = le[jj];
                rank += (o > sv) || (o == sv && jj < tid);
            }
            out_mask[b * 32 + tid] = (rank < K) ? 1 : 0;
        }
    } else {
        // squash(s + bias): fin 1 -> w += v ; fin 2 -> out_v = v
        #pragma unroll
        for (int half = 0; half < 2; ++half) {
            int jj = half * 16 + (tid >> 4), n = tid & 15;
            int idx = (b * J_ + jj) * N_ + n;
            float sv = atomicAdd(&s_out[idx], 0.f);
            float rs = sv;
            for (int k = 8; k; k >>= 1) rs += __shfl_xor(rs, k);
            float sb = (rs == 0.f) ? 0.f : sv + bias[jj * N_ + n];
            float sq = sb * sb;
            for (int k = 8; k; k >>= 1) sq += __shfl_xor(sq, k);
            float v = (sq / (1.f + sq)) * (sb / sqrtf(sq + 1e-8f));
            if (fin == 1) w[idx] += v;
            else         out_v[idx] = v;
        }
    }
}

extern "C" void kernel_launch(void* const* d_in, const int* in_sizes, int n_in,
                              void* d_out, int out_size, void* d_ws, size_t ws_size,
                              hipStream_t stream) {
    const float* U    = (const float*)d_in[0];
    const float* bias = (const float*)d_in[1];
    float* ws  = (float*)d_ws;
    float* out = (float*)d_out;
    float* ent = out + B_ * J_ * N_;

    float* w   = ws + OFF_W;
    float* s1  = ws + OFF_S1;
    float* s2  = ws + OFF_S2;
    float* sc0 = ws + OFF_SC0;
    float* sc1 = ws + OFF_SC1;
    int*   m0  = (int*)(ws + OFF_M0);
    int*   m1  = (int*)(ws + OFF_M1);
    int*   tk  = (int*)(ws + OFF_TK);

    // D1: zero (folded) + s0 sum + squash -> w
    sumv_kernel<<<B_ * J_, 256, 0, stream>>>(U, bias, ws, ent);

    // D2: scores0 (32 planes) + fused top-20 -> m0
    pass_kernel<<<B_ * NT, 256, 0, stream>>>(U, w, nullptr, sc0, nullptr, ent, 0, 0,
                                             tk + 0 * B_, m0, 20, bias, nullptr, 0);

    // D3: iter1 masked softmax -> s1, entropy1 (20 planes) + fused w += squash(s1+bias)
    pass_kernel<<<B_ * NT, 256, 0, stream>>>(U, w, m0, nullptr, s1, ent, 1, 1,
                                             tk + 1 * B_, nullptr, 0, bias, nullptr, 1);

    // D4: scores1 (20 planes) + fused top-12 -> m1
    pass_kernel<<<B_ * NT, 256, 0, stream>>>(U, w, m0, sc1, nullptr, ent, 0, 0,
                                             tk + 2 * B_, m1, 12, bias, nullptr, 0);

    // D5: iter2 masked softmax -> s2, entropy2 (12 planes) + fused out = squash(s2+bias)
    pass_kernel<<<B_ * NT, 256, 0, stream>>>(U, w, m1, nullptr, s2, ent, 2, 1,
                                             tk + 3 * B_, nullptr, 0, bias, out, 2);
}

// Round 9
// 573.914 us; speedup vs baseline: 2.0358x; 2.0358x over previous
//
#include <hip/hip_runtime.h>
#include <math.h>

#define B_ 128
#define J_ 32
#define I_ 1152
#define N_ 16
#define TI 8           // i per stage step (halved -> 18 KB LDS -> 8 blocks/CU)
#define STEPS 8        // stage steps per block -> 64 i per block
#define NT (I_/(TI*STEPS))   // 18 blocks per example in i

// ws layout (float offsets)
#define OFF_W   0
#define OFF_S1  65536
#define OFF_S2  131072
#define OFF_SC0 262144
#define OFF_SC1 266240
#define OFF_M0  270336
#define OFF_M1  274432

// ---------------------------------------------------------------------------
// Dispatch 1: zero (folded) + s0[b,j] = sum_i U, fused squash -> w.
__global__ __launch_bounds__(256) void sumv_kernel(const float* __restrict__ U,
        const float* __restrict__ bias, float* __restrict__ ws,
        float* __restrict__ ent) {
    int bj  = blockIdx.x;
    int b = bj >> 5, j = bj & 31;
    int tid = threadIdx.x;           // 256
    int gb = bj * 256 + tid;

    // folded zeroing (single writer per slot; consumers are later dispatches)
    if (gb < 2 * 65536) ws[OFF_S1 + gb] = 0.f;                 // s1, s2
    if (gb < 2 * 4096)  ws[OFF_SC0 + gb] = 0.f;                // sc0, sc1
    if (gb < B_) {                                             // entropy
        ent[gb * 3]     = logf(32.f);
        ent[gb * 3 + 1] = 0.f;
        ent[gb * 3 + 2] = 0.f;
    }

    int nc  = tid & 3;
    int ip  = tid >> 2;              // 0..63
    const float4* base = (const float4*)(U + (size_t)bj * I_ * N_);
    float4 acc = make_float4(0.f, 0.f, 0.f, 0.f);
    for (int i = ip; i < I_; i += 64) {
        float4 u = base[i * 4 + nc];
        acc.x += u.x; acc.y += u.y; acc.z += u.z; acc.w += u.w;
    }
    __shared__ float4 lds[256];
    lds[nc * 64 + ip] = acc;
    __syncthreads();
    for (int s = 32; s >= 1; s >>= 1) {
        if (ip < s) {
            float4 a = lds[nc * 64 + ip], c = lds[nc * 64 + ip + s];
            a.x += c.x; a.y += c.y; a.z += c.z; a.w += c.w;
            lds[nc * 64 + ip] = a;
        }
        __syncthreads();
    }
    // fused vupdate mode 0: v0 = squash(s0/32 + bias), w = v0
    if (tid < 16) {                  // n = tid
        float sv = ((float*)&lds[(tid >> 2) * 64])[tid & 3] * (1.f / 32.f);
        float rs = sv;
        for (int k = 8; k; k >>= 1) rs += __shfl_xor(rs, k);
        float sb = (rs == 0.f) ? 0.f : sv + bias[j * N_ + tid];
        float sq = sb * sb;
        for (int k = 8; k; k >>= 1) sq += __shfl_xor(sq, k);
        float v = (sq / (1.f + sq)) * (sb / sqrtf(sq + 1e-8f));
        (ws + OFF_W)[(b * J_ + j) * N_ + tid] = v;
    }
}

// ---------------------------------------------------------------------------
// squash + w update. mode 1=update (w+=v), 2=final (out=v)
__global__ void vupdate_kernel(const float* __restrict__ s, const float* __restrict__ bias,
                               float* __restrict__ w, float* __restrict__ out_v,
                               float* __restrict__ ent, float scale, int mode) {
    int b = blockIdx.x;
    int tid = threadIdx.x;           // 512: j=tid>>4, n=tid&15
    int j = tid >> 4, n = tid & 15;
    int idx = (b * J_ + j) * N_ + n;
    float sv = s[idx] * scale;
    float rs = sv;
    for (int k = 8; k; k >>= 1) rs += __shfl_xor(rs, k);
    float sb = (rs == 0.f) ? 0.f : sv + bias[j * N_ + n];
    float sq = sb * sb;
    for (int k = 8; k; k >>= 1) sq += __shfl_xor(sq, k);
    float v = (sq / (1.f + sq)) * (sb / sqrtf(sq + 1e-8f));
    if (mode == 1) {
        w[idx] += v;
    } else {
        out_v[idx] = v;
    }
}

// ---------------------------------------------------------------------------
// Streaming pass, LDS-staged, plane-compacted. 18 KB LDS -> 8 blocks/CU.
// mode 0: scores[b,j] += sum_i p ;  mode 1: s[b,j,n] += sum_i p*U, entropy accum.
__global__ __launch_bounds__(256) void pass_kernel(
        const float* __restrict__ U, const float* __restrict__ w,
        const int* __restrict__ mask, float* __restrict__ scores,
        float* __restrict__ s_out, float* __restrict__ ent,
        int ent_idx, int mode) {
    // staging buffer: up to 32 compact j-planes x (TI*4 + 1 pad) float4
    __shared__ float4 lds[J_ * (TI * 4 + 1)];   // 32*33*16 = 16,896 B
    __shared__ float le[256];
    __shared__ int jlist[32];
    __shared__ int posj[32];
    __shared__ int nact_s;

    int bid = blockIdx.x;
    int b = bid / NT, chunk = bid % NT;
    int i0 = chunk * (TI * STEPS);
    int tid = threadIdx.x;           // 256
    int j = tid & 31, sub = tid >> 5;

    // compact active-j list
    if (tid < 32) {
        int act = mask ? (mask[b * J_ + tid] != 0) : 1;
        unsigned long long bal = __ballot(act);     // lanes 32..63 contribute 0
        unsigned m32 = (unsigned)bal;
        int p = __popc(m32 & ((1u << tid) - 1));
        if (act) jlist[p] = tid;
        posj[tid] = act ? p : -1;
        if (tid == 0) nact_s = __popc(m32);
    }
    __syncthreads();
    int nact = nact_s;
    int pj = posj[j];
    bool active = pj >= 0;
    int pjc = active ? pj : 0;       // safe plane for inactive lanes (e forced 0)

    const float4* wp = (const float4*)(w + (b * J_ + j) * N_);
    float4 w0 = wp[0], w1 = wp[1], w2 = wp[2], w3 = wp[3];

    float acc_sc = 0.f, acc_ent = 0.f;
    float4 a0 = make_float4(0,0,0,0), a1 = a0, a2 = a0, a3 = a0;

    const float4* Ub = (const float4*)U;
    int tot = nact * (TI * 4);       // float4 per step (nact*32)

    for (int st = 0; st < STEPS; ++st) {
        int ibase = i0 + st * TI;
        // ---- stage: only active planes, coalesced global -> LDS
        for (int f = tid; f < tot; f += 256) {
            int jc = f >> 5;             // compact plane index (32 float4/plane)
            int q  = f & 31;             // i_loc*4 + c
            lds[jc * (TI * 4 + 1) + q] =
                Ub[((size_t)(b * J_ + jlist[jc]) * I_ + ibase) * 4 + q];
        }
        __syncthreads();
        // ---- compute from LDS: one i per thread per step (ii = sub)
        {
            const float4* up = &lds[pjc * (TI * 4 + 1) + sub * 4];
            float4 u0 = up[0], u1 = up[1], u2 = up[2], u3 = up[3];
            float y = u0.x * w0.x + u0.y * w0.y + u0.z * w0.z + u0.w * w0.w
                    + u1.x * w1.x + u1.y * w1.y + u1.z * w1.z + u1.w * w1.w
                    + u2.x * w2.x + u2.y * w2.y + u2.z * w2.z + u2.w * w2.w
                    + u3.x * w3.x + u3.y * w3.y + u3.z * w3.z + u3.w * w3.w;
            float e = active ? __expf(y) : 0.f;
            float Z = e;
            for (int k = 16; k; k >>= 1) Z += __shfl_xor(Z, k);
            float p = e / Z;
            if (mode == 0) {
                acc_sc += p;
            } else {
                a0.x += p * u0.x; a0.y += p * u0.y; a0.z += p * u0.z; a0.w += p * u0.w;
                a1.x += p * u1.x; a1.y += p * u1.y; a1.z += p * u1.z; a1.w += p * u1.w;
                a2.x += p * u2.x; a2.y += p * u2.y; a2.z += p * u2.z; a2.w += p * u2.w;
                a3.x += p * u3.x; a3.y += p * u3.y; a3.z += p * u3.z; a3.w += p * u3.w;
                acc_ent += p * (y - __logf(Z));   // p*log(p), exact 0 for p==0
            }
        }
        __syncthreads();   // LDS reused next step
    }

    if (mode == 0) {
        le[tid] = acc_sc;
        __syncthreads();
        if (tid < 32) {
            float t = 0.f;
            for (int s = 0; s < 8; s++) t += le[s * 32 + tid];
            atomicAdd(&scores[b * J_ + tid], t);
        }
    } else {
        float* ls = (float*)lds;          // reuse staging buffer (4224 floats >= 4096)
        float* myl = ls + tid * 16;
        ((float4*)myl)[0] = a0; ((float4*)myl)[1] = a1;
        ((float4*)myl)[2] = a2; ((float4*)myl)[3] = a3;
        le[tid] = acc_ent;
        __syncthreads();
        for (int idx = tid; idx < 512; idx += 256) {
            int jj = idx >> 4, nn = idx & 15;
            float t = 0.f;
            for (int s = 0; s < 8; s++) t += ls[(s * 32 + jj) * 16 + nn];
            atomicAdd(&s_out[(b * J_ + jj) * N_ + nn], t);
        }
        for (int s = 128; s >= 1; s >>= 1) {
            if (tid < s) le[tid] += le[tid + s];
            __syncthreads();
        }
        if (tid == 0) atomicAdd(&ent[b * 3 + ent_idx], -le[0] * (1.f / (float)I_));
    }
}

// ---------------------------------------------------------------------------
// Stable top-K over 32 scores per example (tie-break: lower index).
__global__ void topk_kernel(const float* __restrict__ scores, int* __restrict__ mask, int K) {
    int b = blockIdx.x;
    int tid = threadIdx.x;   // 64, first 32 active
    __shared__ float ls[32];
    if (tid < 32) ls[tid] = scores[b * 32 + tid];
    __syncthreads();
    if (tid < 32) {
        float sv = ls[tid];
        int rank = 0;
        for (int jj = 0; jj < 32; jj++) {
            float o = ls[jj];
            rank += (o > sv) || (o == sv && jj < tid);
        }
        mask[b * 32 + tid] = (rank < K) ? 1 : 0;
    }
}

extern "C" void kernel_launch(void* const* d_in, const int* in_sizes, int n_in,
                              void* d_out, int out_size, void* d_ws, size_t ws_size,
                              hipStream_t stream) {
    const float* U    = (const float*)d_in[0];
    const float* bias = (const float*)d_in[1];
    float* ws  = (float*)d_ws;
    float* out = (float*)d_out;
    float* ent = out + B_ * J_ * N_;

    float* w   = ws + OFF_W;
    float* s1  = ws + OFF_S1;
    float* s2  = ws + OFF_S2;
    float* sc0 = ws + OFF_SC0;
    float* sc1 = ws + OFF_SC1;
    int*   m0  = (int*)(ws + OFF_M0);
    int*   m1  = (int*)(ws + OFF_M1);

    // D1: zero (folded) + s0 sum + squash -> w
    sumv_kernel<<<B_ * J_, 256, 0, stream>>>(U, bias, ws, ent);

    // D2: scores0 (32 planes)
    pass_kernel<<<B_ * NT, 256, 0, stream>>>(U, w, nullptr, sc0, nullptr, nullptr, 0, 0);
    // D3: top-20 mask
    topk_kernel<<<B_, 64, 0, stream>>>(sc0, m0, 20);

    // D4: iter1 masked softmax -> s1, entropy1 (20 planes)
    pass_kernel<<<B_ * NT, 256, 0, stream>>>(U, w, m0, nullptr, s1, ent, 1, 1);
    // D5: w += squash(s1 + bias)
    vupdate_kernel<<<B_, 512, 0, stream>>>(s1, bias, w, nullptr, ent, 1.f, 1);

    // D6: scores1 (20 planes)
    pass_kernel<<<B_ * NT, 256, 0, stream>>>(U, w, m0, sc1, nullptr, nullptr, 0, 0);
    // D7: top-12 mask
    topk_kernel<<<B_, 64, 0, stream>>>(sc1, m1, 12);

    // D8: iter2 masked softmax -> s2, entropy2 (12 planes)
    pass_kernel<<<B_ * NT, 256, 0, stream>>>(U, w, m1, nullptr, s2, ent, 2, 1);
    // D9: out = squash(s2 + bias)
    vupdate_kernel<<<B_, 512, 0, stream>>>(s2, bias, nullptr, out, ent, 1.f, 2);
}